// Round 1
// baseline (25965.601 us; speedup 1.0000x reference)
//
#include <hip/hip_runtime.h>
#include <cstdint>
#include <cstddef>

// ---------------------------------------------------------------------------
// VanillaRNNTrajectoryPredictor — persistent weight-stationary RNN on MI355X
// B=4096, E=H=512, L=2, T_enc=33 (32 veh + 1 main), T_dec=60, O=2
// 256 blocks x 256 threads; each block owns 16 batch rows for the whole
// sequence. Hidden state in LDS (bf16, XOR-swizzled). Weights packed once
// per launch into MFMA fragment order in d_ws (bf16).
// ---------------------------------------------------------------------------

typedef __bf16 bf16x8 __attribute__((ext_vector_type(8)));
typedef float  f32x4  __attribute__((ext_vector_type(4)));

#define SZ   262144   // 512*512 elements per packed weight matrix
#define XDIM 198      // 6 + 32*6 input feature columns

__device__ __host__ __forceinline__ unsigned short f2bf(float x) {
  uint32_t u = __builtin_bit_cast(uint32_t, x);
  u = (u + 0x7FFFu + ((u >> 16) & 1u)) >> 16;   // round-to-nearest-even
  return (unsigned short)u;
}

// Pack a row-major [N][Ksrc] f32 matrix into bf16 MFMA-fragment order:
// dst[((ntile*Kst + kstep)*64 + lane)*8 + i] = W[ntile*16 + (lane&15)]
//                                               [kstep*32 + ((lane>>4)&3)*8 + i]
// Rows >= N and cols >= Ksrc are zero-padded (Kpad = padded K, mult of 32).
__global__ void pack_w(const float* __restrict__ src, unsigned short* __restrict__ dst,
                       int N, int Ksrc, int Kpad) {
  int idx  = blockIdx.x * 256 + threadIdx.x;
  int Npad = (N + 15) & ~15;
  int total = Npad * Kpad;
  if (idx >= total) return;
  int n = idx / Kpad, k = idx - n * Kpad;
  float v = (n < N && k < Ksrc) ? src[n * Ksrc + k] : 0.f;
  int ntile = n >> 4, kstep = k >> 5, i = k & 7;
  int lane  = (((k >> 3) & 3) << 4) | (n & 15);
  int Kst   = Kpad >> 5;
  dst[((((ntile * Kst) + kstep) * 64 + lane) << 3) + i] = f2bf(v);
}

// LDS fragment read from swizzled [16][512] bf16 buffer.
// element (m,k) stored at ushort index  m*512 + (k ^ ((m&7)<<3))
// (XOR on bits 3..5 of k == byte-bit4..6 -> breaks the 1024B-row-stride
//  bank conflict; 8 consecutive k stay a contiguous 16B chunk)
__device__ __forceinline__ bf16x8 lds_frag(const unsigned short* buf, int m, int k) {
  int idx = m * 512 + (k ^ ((m & 7) << 3));
  return *reinterpret_cast<const bf16x8*>(buf + idx);
}

// One GEMM contribution: acc[16 x 512-wave-slice] += A(16x512, LDS) * W^T.
// W packed as above (32 ntiles x 16 ksteps). Wave wv covers cols [wv*128, +128).
__device__ __forceinline__ void gemm_part(f32x4 acc[8], const unsigned short* Abuf,
                                          const unsigned short* __restrict__ Wp,
                                          int lane, int wv) {
  const int m    = lane & 15;
  const int ksub = (lane >> 4) << 3;
#pragma unroll
  for (int ks = 0; ks < 16; ++ks) {
    bf16x8 a = lds_frag(Abuf, m, ks * 32 + ksub);
#pragma unroll
    for (int nf = 0; nf < 8; ++nf) {
      const bf16x8* bp = reinterpret_cast<const bf16x8*>(
          Wp + ((((wv * 8 + nf) * 16) + ks) * 64 + lane) * 8);
      acc[nf] = __builtin_amdgcn_mfma_f32_16x16x32_bf16(a, *bp, acc[nf], 0, 0, 0);
    }
  }
}

__device__ __forceinline__ void init_acc(f32x4 acc[8], const float* __restrict__ b0,
                                         const float* __restrict__ b1, int lane, int wv) {
#pragma unroll
  for (int nf = 0; nf < 8; ++nf) {
    int col = wv * 128 + nf * 16 + (lane & 15);
    float s = b0[col] + (b1 ? b1[col] : 0.f);
    acc[nf] = (f32x4){s, s, s, s};
  }
}

// C/D layout (verified m89/m91): col = lane&15, row = (lane>>4)*4 + reg.
template <int ACT>  // 0 = tanh, 1 = relu
__device__ __forceinline__ void writeback(unsigned short* dst, const f32x4 acc[8],
                                          int lane, int wv) {
#pragma unroll
  for (int nf = 0; nf < 8; ++nf) {
#pragma unroll
    for (int j = 0; j < 4; ++j) {
      float v = acc[nf][j];
      v = (ACT == 0) ? tanhf(v) : fmaxf(v, 0.f);
      int row = ((lane >> 4) << 2) + j;
      int col = wv * 128 + nf * 16 + (lane & 15);
      dst[row * 512 + (col ^ ((row & 7) << 3))] = f2bf(v);
    }
  }
}

__global__ __launch_bounds__(256) void rnn_main(
    const float* __restrict__ x,
    const unsigned short* __restrict__ wp,
    const float* __restrict__ enc_bih, const float* __restrict__ enc_bhh,
    const float* __restrict__ dec_bih, const float* __restrict__ dec_bhh,
    const float* __restrict__ head_b1, const float* __restrict__ head_b2,
    const float* __restrict__ emb_main_b, const float* __restrict__ emb_veh_b,
    float* __restrict__ out) {
  __shared__ alignas(16) unsigned short INP[16 * 512];
  __shared__ alignas(16) unsigned short H0[16 * 512];
  __shared__ alignas(16) unsigned short H1[16 * 512];
  __shared__ alignas(16) unsigned short XA[16 * 48];  // stride 48 -> conflict-free

  const int tid  = threadIdx.x;
  const int lane = tid & 63;
  const int wv   = tid >> 6;
  const int row0 = blockIdx.x * 16;

  const unsigned short* encWih0 = wp + 0 * SZ;
  const unsigned short* encWih1 = wp + 1 * SZ;
  const unsigned short* encWhh0 = wp + 2 * SZ;
  const unsigned short* encWhh1 = wp + 3 * SZ;
  const unsigned short* decWih0 = wp + 4 * SZ;
  const unsigned short* decWih1 = wp + 5 * SZ;
  const unsigned short* decWhh0 = wp + 6 * SZ;
  const unsigned short* decWhh1 = wp + 7 * SZ;
  const unsigned short* headW1p = wp + 8 * SZ;
  const unsigned short* headW2p = wp + 9 * SZ;
  const unsigned short* vehp    = wp + 9 * SZ + 8192;
  const unsigned short* mainp   = wp + 9 * SZ + 8192 + 16384;

  for (int i = tid; i < 16 * 512; i += 256) { H0[i] = 0; H1[i] = 0; }
  __syncthreads();

  f32x4 acc[8];

  // ---------------- encoder: 33 steps (t<32: vehicle tokens, t==32: main) ----
  for (int t = 0; t < 33; ++t) {
    for (int i = tid; i < 16 * 48; i += 256) XA[i] = 0;
    __syncthreads();
    if (tid < 96) {
      int m = tid / 6, kk = tid - m * 6;
      int cx = (t < 32) ? (6 + t * 6 + kk) : kk;
      XA[m * 48 + kk] = f2bf(x[(size_t)(row0 + m) * XDIM + cx]);
    }
    __syncthreads();
    // embedding GEMM (K padded 6->32, single kstep), tanh -> INP
    {
      const unsigned short* We = (t < 32) ? vehp : mainp;
      const float* be          = (t < 32) ? emb_veh_b : emb_main_b;
      init_acc(acc, be, nullptr, lane, wv);
      int m = lane & 15, ksub = (lane >> 4) << 3;
      bf16x8 a = *reinterpret_cast<const bf16x8*>(XA + m * 48 + ksub);
#pragma unroll
      for (int nf = 0; nf < 8; ++nf) {
        const bf16x8* bp = reinterpret_cast<const bf16x8*>(
            We + (((wv * 8 + nf) * 1) * 64 + lane) * 8);
        acc[nf] = __builtin_amdgcn_mfma_f32_16x16x32_bf16(a, *bp, acc[nf], 0, 0, 0);
      }
      __syncthreads();
      writeback<0>(INP, acc, lane, wv);
      __syncthreads();
    }
    // layer 0: h0 = tanh(INP@Wih0^T + bih0 + H0@Whh0^T + bhh0)
    init_acc(acc, enc_bih, enc_bhh, lane, wv);
    gemm_part(acc, INP, encWih0, lane, wv);
    gemm_part(acc, H0, encWhh0, lane, wv);
    __syncthreads();
    writeback<0>(H0, acc, lane, wv);
    __syncthreads();
    // layer 1
    init_acc(acc, enc_bih + 512, enc_bhh + 512, lane, wv);
    gemm_part(acc, H0, encWih1, lane, wv);
    gemm_part(acc, H1, encWhh1, lane, wv);
    __syncthreads();
    writeback<0>(H1, acc, lane, wv);
    __syncthreads();
  }

  // ---------------- decoder: 60 steps; input = previous top (H1) ------------
  for (int t = 0; t < 60; ++t) {
    init_acc(acc, dec_bih, dec_bhh, lane, wv);
    gemm_part(acc, H1, decWih0, lane, wv);
    gemm_part(acc, H0, decWhh0, lane, wv);
    __syncthreads();
    writeback<0>(H0, acc, lane, wv);
    __syncthreads();

    init_acc(acc, dec_bih + 512, dec_bhh + 512, lane, wv);
    gemm_part(acc, H0, decWih1, lane, wv);
    gemm_part(acc, H1, decWhh1, lane, wv);
    __syncthreads();
    writeback<0>(H1, acc, lane, wv);
    __syncthreads();

    // head layer 1: relu(H1@W1^T + b1) -> INP (reused as scratch)
    init_acc(acc, head_b1, nullptr, lane, wv);
    gemm_part(acc, H1, headW1p, lane, wv);
    __syncthreads();
    writeback<1>(INP, acc, lane, wv);
    __syncthreads();

    // head layer 2 (N=2 padded to 16): wave 0 only, 4 interleaved acc chains
    if (wv == 0) {
      int m = lane & 15, ksub = (lane >> 4) << 3;
      f32x4 a2[4];
#pragma unroll
      for (int c = 0; c < 4; ++c) a2[c] = (f32x4){0.f, 0.f, 0.f, 0.f};
#pragma unroll
      for (int ks = 0; ks < 16; ++ks) {
        bf16x8 a = lds_frag(INP, m, ks * 32 + ksub);
        const bf16x8* bp =
            reinterpret_cast<const bf16x8*>(headW2p + (ks * 64 + lane) * 8);
        a2[ks & 3] = __builtin_amdgcn_mfma_f32_16x16x32_bf16(a, *bp, a2[ks & 3], 0, 0, 0);
      }
      f32x4 s = a2[0] + a2[1] + a2[2] + a2[3];
      if (m < 2) {
        float b2v = head_b2[m];
#pragma unroll
        for (int j = 0; j < 4; ++j) {
          int r = row0 + ((lane >> 4) << 2) + j;
          out[(size_t)r * 120 + t * 2 + m] = tanhf(s[j] + b2v);
        }
      }
    }
    // wave0 rejoins at the next step's post-GEMM barrier; no INP writer
    // occurs before the next head1 (which is 2 barriers away). Safe.
  }
}

extern "C" void kernel_launch(void* const* d_in, const int* in_sizes, int n_in,
                              void* d_out, int out_size, void* d_ws, size_t ws_size,
                              hipStream_t stream) {
  const float* x          = (const float*)d_in[0];
  const float* emb_main_W = (const float*)d_in[1];
  const float* emb_main_b = (const float*)d_in[2];
  const float* emb_veh_W  = (const float*)d_in[3];
  const float* emb_veh_b  = (const float*)d_in[4];
  const float* enc_Wih    = (const float*)d_in[5];
  const float* enc_Whh    = (const float*)d_in[6];
  const float* enc_bih    = (const float*)d_in[7];
  const float* enc_bhh    = (const float*)d_in[8];
  const float* dec_Wih    = (const float*)d_in[9];
  const float* dec_Whh    = (const float*)d_in[10];
  const float* dec_bih    = (const float*)d_in[11];
  const float* dec_bhh    = (const float*)d_in[12];
  const float* head_W1    = (const float*)d_in[13];
  const float* head_b1    = (const float*)d_in[14];
  const float* head_W2    = (const float*)d_in[15];
  const float* head_b2    = (const float*)d_in[16];

  unsigned short* wp = (unsigned short*)d_ws;   // needs 9*SZ + 8192 + 2*16384 ushorts ~ 4.8 MB

  dim3 blk(256);
  auto P = [&](const float* src, unsigned short* dst) {
    hipLaunchKernelGGL(pack_w, dim3(1024), blk, 0, stream, src, dst, 512, 512, 512);
  };
  P(enc_Wih + 0 * SZ, wp + 0 * SZ);
  P(enc_Wih + 1 * SZ, wp + 1 * SZ);
  P(enc_Whh + 0 * SZ, wp + 2 * SZ);
  P(enc_Whh + 1 * SZ, wp + 3 * SZ);
  P(dec_Wih + 0 * SZ, wp + 4 * SZ);
  P(dec_Wih + 1 * SZ, wp + 5 * SZ);
  P(dec_Whh + 0 * SZ, wp + 6 * SZ);
  P(dec_Whh + 1 * SZ, wp + 7 * SZ);
  P(head_W1, wp + 8 * SZ);
  hipLaunchKernelGGL(pack_w, dim3(32), blk, 0, stream, head_W2, wp + 9 * SZ, 2, 512, 512);
  hipLaunchKernelGGL(pack_w, dim3(64), blk, 0, stream, emb_veh_W, wp + 9 * SZ + 8192, 512, 6, 32);
  hipLaunchKernelGGL(pack_w, dim3(64), blk, 0, stream, emb_main_W, wp + 9 * SZ + 8192 + 16384, 512, 6, 32);

  hipLaunchKernelGGL(rnn_main, dim3(256), dim3(256), 0, stream,
                     x, (const unsigned short*)wp, enc_bih, enc_bhh, dec_bih, dec_bhh,
                     head_b1, head_b2, emb_main_b, emb_veh_b, (float*)d_out);
}

// Round 2
// 12873.769 us; speedup vs baseline: 2.0169x; 2.0169x over previous
//
#include <hip/hip_runtime.h>
#include <cstdint>
#include <cstddef>

// ---------------------------------------------------------------------------
// VanillaRNNTrajectoryPredictor — persistent weight-stationary RNN on MI355X
// B=4096, E=H=512, L=2, T_enc=33 (32 veh + 1 main), T_dec=60, O=2
// 256 blocks x 1024 threads (16 waves); each block owns 16 batch rows for the
// whole sequence; each wave owns a 32-column N-slice. Hidden state in LDS
// (bf16, XOR-swizzled). Weights packed once per launch into MFMA fragment
// order in d_ws (bf16). A per-step soft grid barrier keeps all blocks in the
// same time step so per-XCD L2 holds the phase's weight set (~2.5 MB < 4 MB).
// ---------------------------------------------------------------------------

typedef __bf16 bf16x8 __attribute__((ext_vector_type(8)));
typedef float  f32x4  __attribute__((ext_vector_type(4)));

#define SZ   262144   // 512*512 elements per packed weight matrix
#define XDIM 198      // 6 + 32*6 input feature columns
#define NF   2        // MFMA n-fragments per wave (16 waves x 2 x 16 = 512 cols)

// d_ws layout (ushort elements): 9*SZ (big mats) + 8192 (headW2) + 2*16384 (emb)
#define WS_USHORTS (9 * SZ + 8192 + 2 * 16384)
#define CTR_BYTE_OFF ((size_t)WS_USHORTS * 2)   // 4,800,512 (4-aligned)
#define NPHASE 96

__device__ __host__ __forceinline__ unsigned short f2bf(float x) {
  uint32_t u = __builtin_bit_cast(uint32_t, x);
  u = (u + 0x7FFFu + ((u >> 16) & 1u)) >> 16;   // round-to-nearest-even
  return (unsigned short)u;
}

// Pack a row-major [N][Ksrc] f32 matrix into bf16 MFMA-fragment order:
// dst[((ntile*Kst + kstep)*64 + lane)*8 + i] = W[ntile*16 + (lane&15)]
//                                               [kstep*32 + ((lane>>4)&3)*8 + i]
__global__ void pack_w(const float* __restrict__ src, unsigned short* __restrict__ dst,
                       int N, int Ksrc, int Kpad) {
  int idx  = blockIdx.x * 256 + threadIdx.x;
  int Npad = (N + 15) & ~15;
  int total = Npad * Kpad;
  if (idx >= total) return;
  int n = idx / Kpad, k = idx - n * Kpad;
  float v = (n < N && k < Ksrc) ? src[n * Ksrc + k] : 0.f;
  int ntile = n >> 4, kstep = k >> 5, i = k & 7;
  int lane  = (((k >> 3) & 3) << 4) | (n & 15);
  int Kst   = Kpad >> 5;
  dst[((((ntile * Kst) + kstep) * 64 + lane) << 3) + i] = f2bf(v);
}

// LDS fragment read from swizzled [16][512] bf16 buffer.
// element (m,k) at ushort index m*512 + (k ^ ((m&7)<<3))
__device__ __forceinline__ bf16x8 lds_frag(const unsigned short* buf, int m, int k) {
  int idx = m * 512 + (k ^ ((m & 7) << 3));
  return *reinterpret_cast<const bf16x8*>(buf + idx);
}

// acc[16 x 32-wave-slice] += A(16x512, LDS) * W^T. Wave wv covers cols
// [wv*32, +32) i.e. ntiles wv*NF .. wv*NF+NF-1.
__device__ __forceinline__ void gemm_part(f32x4 acc[NF], const unsigned short* Abuf,
                                          const unsigned short* __restrict__ Wp,
                                          int lane, int wv) {
  const int m    = lane & 15;
  const int ksub = (lane >> 4) << 3;
#pragma unroll
  for (int ks = 0; ks < 16; ++ks) {
    bf16x8 a = lds_frag(Abuf, m, ks * 32 + ksub);
#pragma unroll
    for (int nf = 0; nf < NF; ++nf) {
      const bf16x8* bp = reinterpret_cast<const bf16x8*>(
          Wp + ((((wv * NF + nf) * 16) + ks) * 64 + lane) * 8);
      acc[nf] = __builtin_amdgcn_mfma_f32_16x16x32_bf16(a, *bp, acc[nf], 0, 0, 0);
    }
  }
}

__device__ __forceinline__ void init_acc(f32x4 acc[NF], const float* __restrict__ b0,
                                         const float* __restrict__ b1, int lane, int wv) {
#pragma unroll
  for (int nf = 0; nf < NF; ++nf) {
    int col = (wv * NF + nf) * 16 + (lane & 15);
    float s = b0[col] + (b1 ? b1[col] : 0.f);
    acc[nf] = (f32x4){s, s, s, s};
  }
}

// C/D layout: col = lane&15, row = (lane>>4)*4 + reg.
template <int ACT>  // 0 = tanh, 1 = relu
__device__ __forceinline__ void writeback(unsigned short* dst, const f32x4 acc[NF],
                                          int lane, int wv) {
#pragma unroll
  for (int nf = 0; nf < NF; ++nf) {
#pragma unroll
    for (int j = 0; j < 4; ++j) {
      float v = acc[nf][j];
      v = (ACT == 0) ? tanhf(v) : fmaxf(v, 0.f);
      int row = ((lane >> 4) << 2) + j;
      int col = (wv * NF + nf) * 16 + (lane & 15);
      dst[row * 512 + (col ^ ((row & 7) << 3))] = f2bf(v);
    }
  }
}

// Soft grid barrier: performance throttle only — correctness never depends on
// it (each block's rows are independent). Bounded spin -> no deadlock even if
// a block times out; device-scope atomics for cross-XCD visibility.
__device__ __forceinline__ void grid_throttle(unsigned int* ctr, int phase,
                                              unsigned int target) {
  __syncthreads();
  if (threadIdx.x == 0) {
    __hip_atomic_fetch_add(&ctr[phase], 1u, __ATOMIC_RELAXED,
                           __HIP_MEMORY_SCOPE_AGENT);
    for (int spin = 0; spin < 400; ++spin) {
      unsigned int v = __hip_atomic_load(&ctr[phase], __ATOMIC_RELAXED,
                                         __HIP_MEMORY_SCOPE_AGENT);
      if (v >= target) break;
      __builtin_amdgcn_s_sleep(16);
    }
  }
  __syncthreads();
}

__global__ __launch_bounds__(1024) void rnn_main(
    const float* __restrict__ x,
    const unsigned short* __restrict__ wp,
    const float* __restrict__ enc_bih, const float* __restrict__ enc_bhh,
    const float* __restrict__ dec_bih, const float* __restrict__ dec_bhh,
    const float* __restrict__ head_b1, const float* __restrict__ head_b2,
    const float* __restrict__ emb_main_b, const float* __restrict__ emb_veh_b,
    float* __restrict__ out, unsigned int* __restrict__ ctr) {
  __shared__ alignas(16) unsigned short INP[16 * 512];
  __shared__ alignas(16) unsigned short H0[16 * 512];
  __shared__ alignas(16) unsigned short H1[16 * 512];
  __shared__ alignas(16) unsigned short XA[16 * 48];  // stride 48 -> conflict-free

  const int tid  = threadIdx.x;
  const int lane = tid & 63;
  const int wv   = tid >> 6;
  const int row0 = blockIdx.x * 16;
  const unsigned int tgt = gridDim.x;

  const unsigned short* encWih0 = wp + 0 * SZ;
  const unsigned short* encWih1 = wp + 1 * SZ;
  const unsigned short* encWhh0 = wp + 2 * SZ;
  const unsigned short* encWhh1 = wp + 3 * SZ;
  const unsigned short* decWih0 = wp + 4 * SZ;
  const unsigned short* decWih1 = wp + 5 * SZ;
  const unsigned short* decWhh0 = wp + 6 * SZ;
  const unsigned short* decWhh1 = wp + 7 * SZ;
  const unsigned short* headW1p = wp + 8 * SZ;
  const unsigned short* headW2p = wp + 9 * SZ;
  const unsigned short* vehp    = wp + 9 * SZ + 8192;
  const unsigned short* mainp   = wp + 9 * SZ + 8192 + 16384;

  for (int i = tid; i < 16 * 512; i += 1024) { H0[i] = 0; H1[i] = 0; }
  __syncthreads();

  f32x4 acc[NF];

  // ---------------- encoder: 33 steps (t<32: vehicle tokens, t==32: main) ----
  for (int t = 0; t < 33; ++t) {
    grid_throttle(ctr, t, tgt);
    for (int i = tid; i < 16 * 48; i += 1024) XA[i] = 0;
    __syncthreads();
    if (tid < 96) {
      int m = tid / 6, kk = tid - m * 6;
      int cx = (t < 32) ? (6 + t * 6 + kk) : kk;
      XA[m * 48 + kk] = f2bf(x[(size_t)(row0 + m) * XDIM + cx]);
    }
    __syncthreads();
    // embedding GEMM (K padded 6->32, single kstep), tanh -> INP
    {
      const unsigned short* We = (t < 32) ? vehp : mainp;
      const float* be          = (t < 32) ? emb_veh_b : emb_main_b;
      init_acc(acc, be, nullptr, lane, wv);
      int m = lane & 15, ksub = (lane >> 4) << 3;
      bf16x8 a = *reinterpret_cast<const bf16x8*>(XA + m * 48 + ksub);
#pragma unroll
      for (int nf = 0; nf < NF; ++nf) {
        const bf16x8* bp = reinterpret_cast<const bf16x8*>(
            We + ((wv * NF + nf) * 64 + lane) * 8);
        acc[nf] = __builtin_amdgcn_mfma_f32_16x16x32_bf16(a, *bp, acc[nf], 0, 0, 0);
      }
      __syncthreads();
      writeback<0>(INP, acc, lane, wv);
      __syncthreads();
    }
    // layer 0: h0 = tanh(INP@Wih0^T + bih0 + H0@Whh0^T + bhh0)
    init_acc(acc, enc_bih, enc_bhh, lane, wv);
    gemm_part(acc, INP, encWih0, lane, wv);
    gemm_part(acc, H0, encWhh0, lane, wv);
    __syncthreads();
    writeback<0>(H0, acc, lane, wv);
    __syncthreads();
    // layer 1
    init_acc(acc, enc_bih + 512, enc_bhh + 512, lane, wv);
    gemm_part(acc, H0, encWih1, lane, wv);
    gemm_part(acc, H1, encWhh1, lane, wv);
    __syncthreads();
    writeback<0>(H1, acc, lane, wv);
    __syncthreads();
  }

  // ---------------- decoder: 60 steps; input = previous top (H1) ------------
  for (int t = 0; t < 60; ++t) {
    grid_throttle(ctr, 33 + t, tgt);
    init_acc(acc, dec_bih, dec_bhh, lane, wv);
    gemm_part(acc, H1, decWih0, lane, wv);
    gemm_part(acc, H0, decWhh0, lane, wv);
    __syncthreads();
    writeback<0>(H0, acc, lane, wv);
    __syncthreads();

    init_acc(acc, dec_bih + 512, dec_bhh + 512, lane, wv);
    gemm_part(acc, H0, decWih1, lane, wv);
    gemm_part(acc, H1, decWhh1, lane, wv);
    __syncthreads();
    writeback<0>(H1, acc, lane, wv);
    __syncthreads();

    // head layer 1: relu(H1@W1^T + b1) -> INP (reused as scratch)
    init_acc(acc, head_b1, nullptr, lane, wv);
    gemm_part(acc, H1, headW1p, lane, wv);
    __syncthreads();
    writeback<1>(INP, acc, lane, wv);
    __syncthreads();

    // head layer 2 (N=2 padded to 16): wave 0 only, 4 interleaved acc chains
    if (wv == 0) {
      int m = lane & 15, ksub = (lane >> 4) << 3;
      f32x4 a2[4];
#pragma unroll
      for (int c = 0; c < 4; ++c) a2[c] = (f32x4){0.f, 0.f, 0.f, 0.f};
#pragma unroll
      for (int ks = 0; ks < 16; ++ks) {
        bf16x8 a = lds_frag(INP, m, ks * 32 + ksub);
        const bf16x8* bp =
            reinterpret_cast<const bf16x8*>(headW2p + (ks * 64 + lane) * 8);
        a2[ks & 3] = __builtin_amdgcn_mfma_f32_16x16x32_bf16(a, *bp, a2[ks & 3], 0, 0, 0);
      }
      f32x4 s = a2[0] + a2[1] + a2[2] + a2[3];
      if (m < 2) {
        float b2v = head_b2[m];
#pragma unroll
        for (int j = 0; j < 4; ++j) {
          int r = row0 + ((lane >> 4) << 2) + j;
          out[(size_t)r * 120 + t * 2 + m] = tanhf(s[j] + b2v);
        }
      }
    }
    // wave0 rejoins at the next step's first barrier; INP is not rewritten
    // until the next head1 writeback (several barriers away). Safe.
  }
}

extern "C" void kernel_launch(void* const* d_in, const int* in_sizes, int n_in,
                              void* d_out, int out_size, void* d_ws, size_t ws_size,
                              hipStream_t stream) {
  const float* x          = (const float*)d_in[0];
  const float* emb_main_W = (const float*)d_in[1];
  const float* emb_main_b = (const float*)d_in[2];
  const float* emb_veh_W  = (const float*)d_in[3];
  const float* emb_veh_b  = (const float*)d_in[4];
  const float* enc_Wih    = (const float*)d_in[5];
  const float* enc_Whh    = (const float*)d_in[6];
  const float* enc_bih    = (const float*)d_in[7];
  const float* enc_bhh    = (const float*)d_in[8];
  const float* dec_Wih    = (const float*)d_in[9];
  const float* dec_Whh    = (const float*)d_in[10];
  const float* dec_bih    = (const float*)d_in[11];
  const float* dec_bhh    = (const float*)d_in[12];
  const float* head_W1    = (const float*)d_in[13];
  const float* head_b1    = (const float*)d_in[14];
  const float* head_W2    = (const float*)d_in[15];
  const float* head_b2    = (const float*)d_in[16];

  unsigned short* wp = (unsigned short*)d_ws;
  unsigned int*  ctr = (unsigned int*)((char*)d_ws + CTR_BYTE_OFF);

  dim3 blk(256);
  auto P = [&](const float* src, unsigned short* dst) {
    hipLaunchKernelGGL(pack_w, dim3(1024), blk, 0, stream, src, dst, 512, 512, 512);
  };
  P(enc_Wih + 0 * SZ, wp + 0 * SZ);
  P(enc_Wih + 1 * SZ, wp + 1 * SZ);
  P(enc_Whh + 0 * SZ, wp + 2 * SZ);
  P(enc_Whh + 1 * SZ, wp + 3 * SZ);
  P(dec_Wih + 0 * SZ, wp + 4 * SZ);
  P(dec_Wih + 1 * SZ, wp + 5 * SZ);
  P(dec_Whh + 0 * SZ, wp + 6 * SZ);
  P(dec_Whh + 1 * SZ, wp + 7 * SZ);
  P(head_W1, wp + 8 * SZ);
  hipLaunchKernelGGL(pack_w, dim3(32), blk, 0, stream, head_W2, wp + 9 * SZ, 2, 512, 512);
  hipLaunchKernelGGL(pack_w, dim3(64), blk, 0, stream, emb_veh_W, wp + 9 * SZ + 8192, 512, 6, 32);
  hipLaunchKernelGGL(pack_w, dim3(64), blk, 0, stream, emb_main_W, wp + 9 * SZ + 8192 + 16384, 512, 6, 32);

  // zero the soft-barrier counters (d_ws is re-poisoned before every call)
  hipMemsetAsync((void*)ctr, 0, NPHASE * sizeof(unsigned int), stream);

  hipLaunchKernelGGL(rnn_main, dim3(256), dim3(1024), 0, stream,
                     x, (const unsigned short*)wp, enc_bih, enc_bhh, dec_bih, dec_bhh,
                     head_b1, head_b2, emb_main_b, emb_veh_b, (float*)d_out, ctr);
}

// Round 4
// 11273.734 us; speedup vs baseline: 2.3032x; 1.1419x over previous
//
#include <hip/hip_runtime.h>
#include <cstdint>
#include <cstddef>

// ---------------------------------------------------------------------------
// VanillaRNNTrajectoryPredictor — persistent weight-stationary RNN on MI355X
// B=4096, E=H=512, L=2, T_enc=33, T_dec=60, O=2
// 128 blocks x 1024 threads (16 waves); each block owns 32 batch rows
// (2 M-tiles sharing every weight-fragment load -> half the weight traffic).
// Hidden state in LDS (bf16, XOR-swizzled). Weights packed once per launch
// into MFMA fragment order in d_ws (bf16).
// No cross-block synchronization of any kind (round-3 post-mortem: the soft
// barrier bought no L2 reuse and was the only timing-dependent machinery).
// The bottleneck is per-block fetch concurrency: each layer's two GEMMs are
// fused into one dual-stream loop with a depth-2 register prefetch ring, and
// __launch_bounds__(1024,4) raises the VGPR cap to 128 for load pipelining.
// ---------------------------------------------------------------------------

typedef __bf16 bf16x8 __attribute__((ext_vector_type(8)));
typedef float  f32x4  __attribute__((ext_vector_type(4)));

#define SZ   262144   // 512*512 elements per packed weight matrix
#define XDIM 198      // 6 + 32*6 input feature columns
#define NF   2        // MFMA n-fragments per wave (16 waves x 2 x 16 = 512 cols)
#define MB   32       // batch rows per block (2 M-tiles)
#define NBLK 128      // 4096 / MB

__device__ __host__ __forceinline__ unsigned short f2bf(float x) {
  uint32_t u = __builtin_bit_cast(uint32_t, x);
  u = (u + 0x7FFFu + ((u >> 16) & 1u)) >> 16;   // round-to-nearest-even
  return (unsigned short)u;
}

// Pack a row-major [N][Ksrc] f32 matrix into bf16 MFMA-fragment order:
// dst[((ntile*Kst + kstep)*64 + lane)*8 + i] = W[ntile*16 + (lane&15)]
//                                               [kstep*32 + ((lane>>4)&3)*8 + i]
__global__ void pack_w(const float* __restrict__ src, unsigned short* __restrict__ dst,
                       int N, int Ksrc, int Kpad) {
  int idx  = blockIdx.x * 256 + threadIdx.x;
  int Npad = (N + 15) & ~15;
  int total = Npad * Kpad;
  if (idx >= total) return;
  int n = idx / Kpad, k = idx - n * Kpad;
  float v = (n < N && k < Ksrc) ? src[n * Ksrc + k] : 0.f;
  int ntile = n >> 4, kstep = k >> 5, i = k & 7;
  int lane  = (((k >> 3) & 3) << 4) | (n & 15);
  int Kst   = Kpad >> 5;
  dst[((((ntile * Kst) + kstep) * 64 + lane) << 3) + i] = f2bf(v);
}

// LDS fragment read from swizzled [MB][512] bf16 buffer.
// element (row,k) at ushort index row*512 + (k ^ ((row&7)<<3)).
// (rows 16+m swizzle identically to rows m since 16 % 8 == 0)
__device__ __forceinline__ bf16x8 lds_frag(const unsigned short* buf, int m, int k) {
  int idx = m * 512 + (k ^ ((m & 7) << 3));
  return *reinterpret_cast<const bf16x8*>(buf + idx);
}

// Weight fragment (ntile, ks) for `lane` from a packed 512x512 matrix.
__device__ __forceinline__ bf16x8 wfrag(const unsigned short* __restrict__ W,
                                        int ntile, int ks, int lane) {
  return *reinterpret_cast<const bf16x8*>(W + (((ntile * 16 + ks) * 64 + lane)) * 8);
}

// Fused dual-stream GEMM: acc += Aa*Wa^T + Ab*Wb^T over K=512, this wave's
// 32-col slice, both M-tiles. 4 weight loads per iter + depth-2 prefetch ring
// -> ~2-3x the weight-fetch concurrency of the single-stream loop.
__device__ __forceinline__ void gemm_pair(f32x4 acc[2][NF],
    const unsigned short* Aa, const unsigned short* __restrict__ Wa,
    const unsigned short* Ab, const unsigned short* __restrict__ Wb,
    int lane, int wv) {
  const int m    = lane & 15;
  const int ksub = (lane >> 4) << 3;
  const int nt0  = wv * NF;
  bf16x8 wa[2][NF], wb[2][NF];
#pragma unroll
  for (int nf = 0; nf < NF; ++nf) {
    wa[0][nf] = wfrag(Wa, nt0 + nf, 0, lane);
    wb[0][nf] = wfrag(Wb, nt0 + nf, 0, lane);
  }
#pragma unroll
  for (int ks = 0; ks < 16; ++ks) {
    const int cur = ks & 1, nxt = cur ^ 1;
    if (ks < 15) {
#pragma unroll
      for (int nf = 0; nf < NF; ++nf) {
        wa[nxt][nf] = wfrag(Wa, nt0 + nf, ks + 1, lane);
        wb[nxt][nf] = wfrag(Wb, nt0 + nf, ks + 1, lane);
      }
    }
    bf16x8 aa0 = lds_frag(Aa, m, ks * 32 + ksub);
    bf16x8 aa1 = lds_frag(Aa + 16 * 512, m, ks * 32 + ksub);
    bf16x8 ab0 = lds_frag(Ab, m, ks * 32 + ksub);
    bf16x8 ab1 = lds_frag(Ab + 16 * 512, m, ks * 32 + ksub);
#pragma unroll
    for (int nf = 0; nf < NF; ++nf) {
      acc[0][nf] = __builtin_amdgcn_mfma_f32_16x16x32_bf16(aa0, wa[cur][nf], acc[0][nf], 0, 0, 0);
      acc[1][nf] = __builtin_amdgcn_mfma_f32_16x16x32_bf16(aa1, wa[cur][nf], acc[1][nf], 0, 0, 0);
      acc[0][nf] = __builtin_amdgcn_mfma_f32_16x16x32_bf16(ab0, wb[cur][nf], acc[0][nf], 0, 0, 0);
      acc[1][nf] = __builtin_amdgcn_mfma_f32_16x16x32_bf16(ab1, wb[cur][nf], acc[1][nf], 0, 0, 0);
    }
  }
}

// Single-stream variant (head layer 1) with the same prefetch ring.
__device__ __forceinline__ void gemm_one(f32x4 acc[2][NF],
    const unsigned short* Aa, const unsigned short* __restrict__ Wa,
    int lane, int wv) {
  const int m    = lane & 15;
  const int ksub = (lane >> 4) << 3;
  const int nt0  = wv * NF;
  bf16x8 wa[2][NF];
#pragma unroll
  for (int nf = 0; nf < NF; ++nf) wa[0][nf] = wfrag(Wa, nt0 + nf, 0, lane);
#pragma unroll
  for (int ks = 0; ks < 16; ++ks) {
    const int cur = ks & 1, nxt = cur ^ 1;
    if (ks < 15) {
#pragma unroll
      for (int nf = 0; nf < NF; ++nf) wa[nxt][nf] = wfrag(Wa, nt0 + nf, ks + 1, lane);
    }
    bf16x8 a0 = lds_frag(Aa, m, ks * 32 + ksub);
    bf16x8 a1 = lds_frag(Aa + 16 * 512, m, ks * 32 + ksub);
#pragma unroll
    for (int nf = 0; nf < NF; ++nf) {
      acc[0][nf] = __builtin_amdgcn_mfma_f32_16x16x32_bf16(a0, wa[cur][nf], acc[0][nf], 0, 0, 0);
      acc[1][nf] = __builtin_amdgcn_mfma_f32_16x16x32_bf16(a1, wa[cur][nf], acc[1][nf], 0, 0, 0);
    }
  }
}

__device__ __forceinline__ void init_acc(f32x4 acc[2][NF], const float* __restrict__ b0,
                                         const float* __restrict__ b1, int lane, int wv) {
#pragma unroll
  for (int nf = 0; nf < NF; ++nf) {
    int col = (wv * NF + nf) * 16 + (lane & 15);
    float s = b0[col] + (b1 ? b1[col] : 0.f);
    acc[0][nf] = (f32x4){s, s, s, s};
    acc[1][nf] = (f32x4){s, s, s, s};
  }
}

// C/D layout: col = lane&15, row(within mtile) = (lane>>4)*4 + reg.
template <int ACT>  // 0 = tanh, 1 = relu
__device__ __forceinline__ void writeback(unsigned short* dst, const f32x4 acc[2][NF],
                                          int lane, int wv) {
#pragma unroll
  for (int mt = 0; mt < 2; ++mt) {
#pragma unroll
    for (int nf = 0; nf < NF; ++nf) {
#pragma unroll
      for (int j = 0; j < 4; ++j) {
        float v = acc[mt][nf][j];
        v = (ACT == 0) ? tanhf(v) : fmaxf(v, 0.f);
        int row = mt * 16 + ((lane >> 4) << 2) + j;
        int col = (wv * NF + nf) * 16 + (lane & 15);
        dst[row * 512 + (col ^ ((row & 7) << 3))] = f2bf(v);
      }
    }
  }
}

__global__ __launch_bounds__(1024, 4) void rnn_main(
    const float* __restrict__ x,
    const unsigned short* __restrict__ wp,
    const float* __restrict__ enc_bih, const float* __restrict__ enc_bhh,
    const float* __restrict__ dec_bih, const float* __restrict__ dec_bhh,
    const float* __restrict__ head_b1, const float* __restrict__ head_b2,
    const float* __restrict__ emb_main_b, const float* __restrict__ emb_veh_b,
    float* __restrict__ out) {
  __shared__ alignas(16) unsigned short INP[MB * 512];
  __shared__ alignas(16) unsigned short H0[MB * 512];
  __shared__ alignas(16) unsigned short H1[MB * 512];
  __shared__ alignas(16) unsigned short XA[MB * 48];

  const int tid  = threadIdx.x;
  const int lane = tid & 63;
  const int wv   = tid >> 6;
  const int row0 = blockIdx.x * MB;

  const unsigned short* encWih0 = wp + 0 * SZ;
  const unsigned short* encWih1 = wp + 1 * SZ;
  const unsigned short* encWhh0 = wp + 2 * SZ;
  const unsigned short* encWhh1 = wp + 3 * SZ;
  const unsigned short* decWih0 = wp + 4 * SZ;
  const unsigned short* decWih1 = wp + 5 * SZ;
  const unsigned short* decWhh0 = wp + 6 * SZ;
  const unsigned short* decWhh1 = wp + 7 * SZ;
  const unsigned short* headW1p = wp + 8 * SZ;
  const unsigned short* headW2p = wp + 9 * SZ;
  const unsigned short* vehp    = wp + 9 * SZ + 8192;
  const unsigned short* mainp   = wp + 9 * SZ + 8192 + 16384;

  for (int i = tid; i < MB * 512; i += 1024) { H0[i] = 0; H1[i] = 0; }
  __syncthreads();

  f32x4 acc[2][NF];

  // ---------------- encoder: 33 steps (t<32: vehicle tokens, t==32: main) ----
  for (int t = 0; t < 33; ++t) {
    for (int i = tid; i < MB * 48; i += 1024) XA[i] = 0;
    __syncthreads();
    if (tid < MB * 6) {
      int m = tid / 6, kk = tid - m * 6;
      int cx = (t < 32) ? (6 + t * 6 + kk) : kk;
      XA[m * 48 + kk] = f2bf(x[(size_t)(row0 + m) * XDIM + cx]);
    }
    __syncthreads();
    // embedding GEMM (K padded 6->32, single kstep), tanh -> INP
    {
      const unsigned short* We = (t < 32) ? vehp : mainp;
      const float* be          = (t < 32) ? emb_veh_b : emb_main_b;
      init_acc(acc, be, nullptr, lane, wv);
      int m = lane & 15, ksub = (lane >> 4) << 3;
      bf16x8 a0 = *reinterpret_cast<const bf16x8*>(XA + m * 48 + ksub);
      bf16x8 a1 = *reinterpret_cast<const bf16x8*>(XA + (16 + m) * 48 + ksub);
#pragma unroll
      for (int nf = 0; nf < NF; ++nf) {
        bf16x8 w = *reinterpret_cast<const bf16x8*>(
            We + ((wv * NF + nf) * 64 + lane) * 8);
        acc[0][nf] = __builtin_amdgcn_mfma_f32_16x16x32_bf16(a0, w, acc[0][nf], 0, 0, 0);
        acc[1][nf] = __builtin_amdgcn_mfma_f32_16x16x32_bf16(a1, w, acc[1][nf], 0, 0, 0);
      }
      __syncthreads();
      writeback<0>(INP, acc, lane, wv);
      __syncthreads();
    }
    // layer 0: H0 = tanh(INP@Wih0^T + bih0 + H0@Whh0^T + bhh0)
    init_acc(acc, enc_bih, enc_bhh, lane, wv);
    gemm_pair(acc, INP, encWih0, H0, encWhh0, lane, wv);
    __syncthreads();
    writeback<0>(H0, acc, lane, wv);
    __syncthreads();
    // layer 1
    init_acc(acc, enc_bih + 512, enc_bhh + 512, lane, wv);
    gemm_pair(acc, H0, encWih1, H1, encWhh1, lane, wv);
    __syncthreads();
    writeback<0>(H1, acc, lane, wv);
    __syncthreads();
  }

  // ---------------- decoder: 60 steps; input = previous top (H1) ------------
  for (int t = 0; t < 60; ++t) {
    // layer 0
    init_acc(acc, dec_bih, dec_bhh, lane, wv);
    gemm_pair(acc, H1, decWih0, H0, decWhh0, lane, wv);
    __syncthreads();
    writeback<0>(H0, acc, lane, wv);
    __syncthreads();

    // layer 1
    init_acc(acc, dec_bih + 512, dec_bhh + 512, lane, wv);
    gemm_pair(acc, H0, decWih1, H1, decWhh1, lane, wv);
    __syncthreads();
    writeback<0>(H1, acc, lane, wv);
    __syncthreads();

    // head layer 1: relu(H1@W1^T + b1) -> INP (reused as scratch)
    init_acc(acc, head_b1, nullptr, lane, wv);
    gemm_one(acc, H1, headW1p, lane, wv);
    __syncthreads();
    writeback<1>(INP, acc, lane, wv);
    __syncthreads();

    // head layer 2 (N=2 padded to 16): waves 0,1 handle mtiles 0,1
    if (wv < 2) {
      const unsigned short* A2 = INP + wv * 16 * 512;
      int m = lane & 15, ksub = (lane >> 4) << 3;
      f32x4 a2[4];
#pragma unroll
      for (int c = 0; c < 4; ++c) a2[c] = (f32x4){0.f, 0.f, 0.f, 0.f};
#pragma unroll
      for (int ks = 0; ks < 16; ++ks) {
        bf16x8 a = lds_frag(A2, m, ks * 32 + ksub);
        const bf16x8* bp =
            reinterpret_cast<const bf16x8*>(headW2p + (ks * 64 + lane) * 8);
        a2[ks & 3] = __builtin_amdgcn_mfma_f32_16x16x32_bf16(a, *bp, a2[ks & 3], 0, 0, 0);
      }
      f32x4 s = a2[0] + a2[1] + a2[2] + a2[3];
      if (m < 2) {
        float b2v = head_b2[m];
#pragma unroll
        for (int j = 0; j < 4; ++j) {
          int r = row0 + wv * 16 + ((lane >> 4) << 2) + j;
          out[(size_t)r * 120 + t * 2 + m] = tanhf(s[j] + b2v);
        }
      }
    }
    // waves 0,1 rejoin at the next phase's pre-writeback __syncthreads; INP
    // is not rewritten until the next head1 writeback (several barriers away,
    // and the intervening gemms touch only H0/H1). Safe.
  }
}

extern "C" void kernel_launch(void* const* d_in, const int* in_sizes, int n_in,
                              void* d_out, int out_size, void* d_ws, size_t ws_size,
                              hipStream_t stream) {
  const float* x          = (const float*)d_in[0];
  const float* emb_main_W = (const float*)d_in[1];
  const float* emb_main_b = (const float*)d_in[2];
  const float* emb_veh_W  = (const float*)d_in[3];
  const float* emb_veh_b  = (const float*)d_in[4];
  const float* enc_Wih    = (const float*)d_in[5];
  const float* enc_Whh    = (const float*)d_in[6];
  const float* enc_bih    = (const float*)d_in[7];
  const float* enc_bhh    = (const float*)d_in[8];
  const float* dec_Wih    = (const float*)d_in[9];
  const float* dec_Whh    = (const float*)d_in[10];
  const float* dec_bih    = (const float*)d_in[11];
  const float* dec_bhh    = (const float*)d_in[12];
  const float* head_W1    = (const float*)d_in[13];
  const float* head_b1    = (const float*)d_in[14];
  const float* head_W2    = (const float*)d_in[15];
  const float* head_b2    = (const float*)d_in[16];

  unsigned short* wp = (unsigned short*)d_ws;   // 9*SZ + 8192 + 2*16384 ushorts ~ 4.8 MB

  dim3 blk(256);
  auto P = [&](const float* src, unsigned short* dst) {
    hipLaunchKernelGGL(pack_w, dim3(1024), blk, 0, stream, src, dst, 512, 512, 512);
  };
  P(enc_Wih + 0 * SZ, wp + 0 * SZ);
  P(enc_Wih + 1 * SZ, wp + 1 * SZ);
  P(enc_Whh + 0 * SZ, wp + 2 * SZ);
  P(enc_Whh + 1 * SZ, wp + 3 * SZ);
  P(dec_Wih + 0 * SZ, wp + 4 * SZ);
  P(dec_Wih + 1 * SZ, wp + 5 * SZ);
  P(dec_Whh + 0 * SZ, wp + 6 * SZ);
  P(dec_Whh + 1 * SZ, wp + 7 * SZ);
  P(head_W1, wp + 8 * SZ);
  hipLaunchKernelGGL(pack_w, dim3(32), blk, 0, stream, head_W2, wp + 9 * SZ, 2, 512, 512);
  hipLaunchKernelGGL(pack_w, dim3(64), blk, 0, stream, emb_veh_W, wp + 9 * SZ + 8192, 512, 6, 32);
  hipLaunchKernelGGL(pack_w, dim3(64), blk, 0, stream, emb_main_W, wp + 9 * SZ + 8192 + 16384, 512, 6, 32);

  hipLaunchKernelGGL(rnn_main, dim3(NBLK), dim3(1024), 0, stream,
                     x, (const unsigned short*)wp, enc_bih, enc_bhh, dec_bih, dec_bhh,
                     head_b1, head_b2, emb_main_b, emb_veh_b, (float*)d_out);
}

// Round 6
// 3171.798 us; speedup vs baseline: 8.1864x; 3.5544x over previous
//
#include <hip/hip_runtime.h>
#include <cstdint>
#include <cstddef>

// ---------------------------------------------------------------------------
// VanillaRNNTrajectoryPredictor — persistent weight-stationary RNN on MI355X
// B=4096, E=H=512, L=2, T_enc=33, T_dec=60, O=2
// 128 blocks x 1024 threads (16 waves); each block owns 32 batch rows
// (2 M-tiles sharing every weight fragment). Hidden state in LDS (bf16,
// XOR-swizzled). Weights packed per launch into [kstep][ntile][lane][8]
// fragment order so each K=32 slice is a contiguous 32 KB block.
//
// Fetch-latency-bound fix (round 5, resubmitted after infra flake):
// weights stream through a double-buffered 2x32KB LDS ring via
// __builtin_amdgcn_global_load_lds (1024 thr x 2 x 16 B per slice), with
// per-kstep  s_waitcnt vmcnt(0) -> barrier -> stage(next) -> compute(cur).
// Slices chain across GEMM and step boundaries so the pipeline never drains.
// LDS = 3*32KB (H0,H1,INP; XA aliases INP) + 64KB ring = 160 KB exactly.
// ---------------------------------------------------------------------------

typedef __bf16 bf16x8 __attribute__((ext_vector_type(8)));
typedef float  f32x4  __attribute__((ext_vector_type(4)));

#define SZ    262144   // 512*512 elements per packed weight matrix
#define XDIM  198      // 6 + 32*6 input feature columns
#define NF    2        // MFMA n-fragments per wave (16 waves x 2 x 16 = 512 cols)
#define MB    32       // batch rows per block (2 M-tiles)
#define NBLK  128      // 4096 / MB
#define SLICE 16384    // ushorts per kstep slice: 32 ntiles * 64 lanes * 8 = 32 KB

__device__ __host__ __forceinline__ unsigned short f2bf(float x) {
  uint32_t u = __builtin_bit_cast(uint32_t, x);
  u = (u + 0x7FFFu + ((u >> 16) & 1u)) >> 16;   // round-to-nearest-even
  return (unsigned short)u;
}

// Pack a row-major [N][Ksrc] f32 matrix into bf16 MFMA-fragment order, slice-
// contiguous: dst[((kstep*NT + ntile)*64 + lane)*8 + i] =
//   W[ntile*16 + (lane&15)][kstep*32 + ((lane>>4)&3)*8 + i],  NT = Npad/16.
__global__ void pack_w(const float* __restrict__ src, unsigned short* __restrict__ dst,
                       int N, int Ksrc, int Kpad) {
  int idx  = blockIdx.x * 256 + threadIdx.x;
  int Npad = (N + 15) & ~15;
  int total = Npad * Kpad;
  if (idx >= total) return;
  int n = idx / Kpad, k = idx - n * Kpad;
  float v = (n < N && k < Ksrc) ? src[n * Ksrc + k] : 0.f;
  int ntile = n >> 4, kstep = k >> 5, i = k & 7;
  int lane  = (((k >> 3) & 3) << 4) | (n & 15);
  int NT    = Npad >> 4;
  dst[((((kstep * NT) + ntile) * 64 + lane) << 3) + i] = f2bf(v);
}

// LDS fragment read from swizzled [MB][512] bf16 buffer.
// element (row,k) at ushort index row*512 + (k ^ ((row&7)<<3)).
__device__ __forceinline__ bf16x8 lds_frag(const unsigned short* buf, int m, int k) {
  int idx = m * 512 + (k ^ ((m & 7) << 3));
  return *reinterpret_cast<const bf16x8*>(buf + idx);
}

// Stage one 32 KB kstep slice: 1024 threads x 2 rounds x 16 B, global->LDS DMA.
// LDS dest is wave-uniform base (+lane*16 in HW); global src is per-lane.
// Packed layout is linear in exactly this order, so LDS mirrors global.
__device__ __forceinline__ void stage_slice(const unsigned short* __restrict__ g,
                                            unsigned short* l, int wv) {
  const int lane = threadIdx.x & 63;
  const unsigned short* g0 = g + (wv * 64 + lane) * 8;
  unsigned short* l0 = l + wv * 64 * 8;   // wave-uniform
  __builtin_amdgcn_global_load_lds((const __attribute__((address_space(1))) void*)g0,
                                   (__attribute__((address_space(3))) void*)l0, 16, 0, 0);
  __builtin_amdgcn_global_load_lds((const __attribute__((address_space(1))) void*)(g0 + 8192),
                                   (__attribute__((address_space(3))) void*)(l0 + 8192), 16, 0, 0);
}

// One LDS-staged GEMM over K=512 (16 slices): acc += A * W^T (this wave's
// 32-col slice, both M-tiles). During each kstep, stages the next slice
// (chaining into Wnextg's slice 0 at the end) into the other ring buffer.
__device__ __forceinline__ void gemm_lds(f32x4 acc[2][NF], const unsigned short* Abuf,
    const unsigned short* __restrict__ Wg, const unsigned short* __restrict__ Wnextg,
    unsigned short* WB0, unsigned short* WB1, int& buf, int lane, int wv) {
  const int m    = lane & 15;
  const int ksub = (lane >> 4) << 3;
  for (int ks = 0; ks < 16; ++ks) {
    asm volatile("s_waitcnt vmcnt(0)" ::: "memory");  // my slice-ks loads done
    __syncthreads();                                   // everyone's done; prev buf free
    unsigned short* cur = buf ? WB1 : WB0;
    unsigned short* nxt = buf ? WB0 : WB1;
    stage_slice(ks < 15 ? (Wg + (ks + 1) * SLICE) : Wnextg, nxt, wv);
    bf16x8 a0 = lds_frag(Abuf, m, ks * 32 + ksub);
    bf16x8 a1 = lds_frag(Abuf + 16 * 512, m, ks * 32 + ksub);
#pragma unroll
    for (int nf = 0; nf < NF; ++nf) {
      bf16x8 w = *reinterpret_cast<const bf16x8*>(cur + ((wv * NF + nf) * 64 + lane) * 8);
      acc[0][nf] = __builtin_amdgcn_mfma_f32_16x16x32_bf16(a0, w, acc[0][nf], 0, 0, 0);
      acc[1][nf] = __builtin_amdgcn_mfma_f32_16x16x32_bf16(a1, w, acc[1][nf], 0, 0, 0);
    }
    buf ^= 1;
  }
}

__device__ __forceinline__ void init_acc(f32x4 acc[2][NF], const float* __restrict__ b0,
                                         const float* __restrict__ b1, int lane, int wv) {
#pragma unroll
  for (int nf = 0; nf < NF; ++nf) {
    int col = (wv * NF + nf) * 16 + (lane & 15);
    float s = b0[col] + (b1 ? b1[col] : 0.f);
    acc[0][nf] = (f32x4){s, s, s, s};
    acc[1][nf] = (f32x4){s, s, s, s};
  }
}

// C/D layout: col = lane&15, row(within mtile) = (lane>>4)*4 + reg.
template <int ACT>  // 0 = tanh, 1 = relu
__device__ __forceinline__ void writeback(unsigned short* dst, const f32x4 acc[2][NF],
                                          int lane, int wv) {
#pragma unroll
  for (int mt = 0; mt < 2; ++mt) {
#pragma unroll
    for (int nf = 0; nf < NF; ++nf) {
#pragma unroll
      for (int j = 0; j < 4; ++j) {
        float v = acc[mt][nf][j];
        v = (ACT == 0) ? tanhf(v) : fmaxf(v, 0.f);
        int row = mt * 16 + ((lane >> 4) << 2) + j;
        int col = (wv * NF + nf) * 16 + (lane & 15);
        dst[row * 512 + (col ^ ((row & 7) << 3))] = f2bf(v);
      }
    }
  }
}

__global__ __launch_bounds__(1024, 4) void rnn_main(
    const float* __restrict__ x,
    const unsigned short* __restrict__ wp,
    const float* __restrict__ enc_bih, const float* __restrict__ enc_bhh,
    const float* __restrict__ dec_bih, const float* __restrict__ dec_bhh,
    const float* __restrict__ head_b1, const float* __restrict__ head_b2,
    const float* __restrict__ emb_main_b, const float* __restrict__ emb_veh_b,
    float* __restrict__ out) {
  __shared__ alignas(16) unsigned short H0[MB * 512];
  __shared__ alignas(16) unsigned short H1[MB * 512];
  __shared__ alignas(16) unsigned short INP[MB * 512];
  __shared__ alignas(16) unsigned short WBUF[2][SLICE];   // total LDS = 160 KB

  unsigned short* XA = INP;   // alias: XA dead once emb writeback lands

  const int tid  = threadIdx.x;
  const int lane = tid & 63;
  const int wv   = tid >> 6;
  const int row0 = blockIdx.x * MB;

  const unsigned short* encWih0 = wp + 0 * SZ;
  const unsigned short* encWih1 = wp + 1 * SZ;
  const unsigned short* encWhh0 = wp + 2 * SZ;
  const unsigned short* encWhh1 = wp + 3 * SZ;
  const unsigned short* decWih0 = wp + 4 * SZ;
  const unsigned short* decWih1 = wp + 5 * SZ;
  const unsigned short* decWhh0 = wp + 6 * SZ;
  const unsigned short* decWhh1 = wp + 7 * SZ;
  const unsigned short* headW1p = wp + 8 * SZ;
  const unsigned short* headW2p = wp + 9 * SZ;
  const unsigned short* vehp    = wp + 9 * SZ + 8192;
  const unsigned short* mainp   = wp + 9 * SZ + 8192 + 16384;

  for (int i = tid; i < MB * 512; i += 1024) { H0[i] = 0; H1[i] = 0; }
  __syncthreads();

  f32x4 acc[2][NF];
  int buf = 0;
  stage_slice(vehp, WBUF[0], wv);   // prologue: emb(t=0) slice in flight

  // ---------------- encoder: 33 steps (t<32: vehicle tokens, t==32: main) ----
  for (int t = 0; t < 33; ++t) {
    // XA fill (aliases INP; INP's last readers finished 2 GEMMs ago)
    for (int i = tid; i < MB * 48; i += 1024) XA[i] = 0;
    __syncthreads();
    if (tid < MB * 6) {
      int m = tid / 6, kk = tid - m * 6;
      int cx = (t < 32) ? (6 + t * 6 + kk) : kk;
      XA[m * 48 + kk] = f2bf(x[(size_t)(row0 + m) * XDIM + cx]);
    }
    __syncthreads();
    // embedding GEMM: single staged slice; chain -> encWih0 slice 0
    {
      const float* be = (t < 32) ? emb_veh_b : emb_main_b;
      init_acc(acc, be, nullptr, lane, wv);
      asm volatile("s_waitcnt vmcnt(0)" ::: "memory");
      __syncthreads();
      unsigned short* cur = buf ? WBUF[1] : WBUF[0];
      unsigned short* nxt = buf ? WBUF[0] : WBUF[1];
      stage_slice(encWih0, nxt, wv);
      int m = lane & 15, ksub = (lane >> 4) << 3;
      bf16x8 a0 = *reinterpret_cast<const bf16x8*>(XA + m * 48 + ksub);
      bf16x8 a1 = *reinterpret_cast<const bf16x8*>(XA + (16 + m) * 48 + ksub);
#pragma unroll
      for (int nf = 0; nf < NF; ++nf) {
        bf16x8 w = *reinterpret_cast<const bf16x8*>(cur + ((wv * NF + nf) * 64 + lane) * 8);
        acc[0][nf] = __builtin_amdgcn_mfma_f32_16x16x32_bf16(a0, w, acc[0][nf], 0, 0, 0);
        acc[1][nf] = __builtin_amdgcn_mfma_f32_16x16x32_bf16(a1, w, acc[1][nf], 0, 0, 0);
      }
      buf ^= 1;
      __syncthreads();
      writeback<0>(INP, acc, lane, wv);   // overwrites XA alias; XA now dead
    }
    // layer 0: H0 = tanh(INP@Wih0^T + bih0 + H0@Whh0^T + bhh0)
    init_acc(acc, enc_bih, enc_bhh, lane, wv);
    gemm_lds(acc, INP, encWih0, encWhh0, WBUF[0], WBUF[1], buf, lane, wv);
    gemm_lds(acc, H0,  encWhh0, encWih1, WBUF[0], WBUF[1], buf, lane, wv);
    __syncthreads();
    writeback<0>(H0, acc, lane, wv);
    // layer 1: H1 = tanh(H0@Wih1^T + ... + H1@Whh1^T + ...)
    const unsigned short* after =
        (t < 31) ? vehp : (t == 31 ? mainp : decWih0);
    init_acc(acc, enc_bih + 512, enc_bhh + 512, lane, wv);
    gemm_lds(acc, H0, encWih1, encWhh1, WBUF[0], WBUF[1], buf, lane, wv);
    gemm_lds(acc, H1, encWhh1, after,   WBUF[0], WBUF[1], buf, lane, wv);
    __syncthreads();
    writeback<0>(H1, acc, lane, wv);
  }

  // ---------------- decoder: 60 steps; input = previous top (H1) ------------
  for (int t = 0; t < 60; ++t) {
    // layer 0
    init_acc(acc, dec_bih, dec_bhh, lane, wv);
    gemm_lds(acc, H1, decWih0, decWhh0, WBUF[0], WBUF[1], buf, lane, wv);
    gemm_lds(acc, H0, decWhh0, decWih1, WBUF[0], WBUF[1], buf, lane, wv);
    __syncthreads();
    writeback<0>(H0, acc, lane, wv);
    // layer 1
    init_acc(acc, dec_bih + 512, dec_bhh + 512, lane, wv);
    gemm_lds(acc, H0, decWih1, decWhh1, WBUF[0], WBUF[1], buf, lane, wv);
    gemm_lds(acc, H1, decWhh1, headW1p, WBUF[0], WBUF[1], buf, lane, wv);
    __syncthreads();
    writeback<0>(H1, acc, lane, wv);
    // head layer 1: relu(H1@W1^T + b1) -> INP ; chain -> next step's decWih0
    init_acc(acc, head_b1, nullptr, lane, wv);
    gemm_lds(acc, H1, headW1p, decWih0, WBUF[0], WBUF[1], buf, lane, wv);
    __syncthreads();
    writeback<1>(INP, acc, lane, wv);
    __syncthreads();   // head2 (waves 0,1) reads INP written by all waves

    // head layer 2 (N=2 padded to 16): waves 0,1 handle mtiles 0,1; W2 is a
    // 16 KB L2-hot stream read directly from global.
    if (wv < 2) {
      const unsigned short* A2 = INP + wv * 16 * 512;
      int m = lane & 15, ksub = (lane >> 4) << 3;
      f32x4 a2[4];
#pragma unroll
      for (int c = 0; c < 4; ++c) a2[c] = (f32x4){0.f, 0.f, 0.f, 0.f};
#pragma unroll
      for (int ks = 0; ks < 16; ++ks) {
        bf16x8 a = lds_frag(A2, m, ks * 32 + ksub);
        const bf16x8* bp =
            reinterpret_cast<const bf16x8*>(headW2p + (ks * 64 + lane) * 8);
        a2[ks & 3] = __builtin_amdgcn_mfma_f32_16x16x32_bf16(a, *bp, a2[ks & 3], 0, 0, 0);
      }
      f32x4 s = a2[0] + a2[1] + a2[2] + a2[3];
      if (m < 2) {
        float b2v = head_b2[m];
#pragma unroll
        for (int j = 0; j < 4; ++j) {
          int r = row0 + wv * 16 + ((lane >> 4) << 2) + j;
          out[(size_t)r * 120 + t * 2 + m] = tanhf(s[j] + b2v);
        }
      }
    }
    // waves >=2 proceed; they rendezvous with waves 0,1 at the next GEMM's
    // kstep-0 barrier, and nothing before that touches INP or WBUF[cur].
  }
  // drain outstanding LDS-DMA before workgroup teardown
  asm volatile("s_waitcnt vmcnt(0)" ::: "memory");
}

extern "C" void kernel_launch(void* const* d_in, const int* in_sizes, int n_in,
                              void* d_out, int out_size, void* d_ws, size_t ws_size,
                              hipStream_t stream) {
  const float* x          = (const float*)d_in[0];
  const float* emb_main_W = (const float*)d_in[1];
  const float* emb_main_b = (const float*)d_in[2];
  const float* emb_veh_W  = (const float*)d_in[3];
  const float* emb_veh_b  = (const float*)d_in[4];
  const float* enc_Wih    = (const float*)d_in[5];
  const float* enc_Whh    = (const float*)d_in[6];
  const float* enc_bih    = (const float*)d_in[7];
  const float* enc_bhh    = (const float*)d_in[8];
  const float* dec_Wih    = (const float*)d_in[9];
  const float* dec_Whh    = (const float*)d_in[10];
  const float* dec_bih    = (const float*)d_in[11];
  const float* dec_bhh    = (const float*)d_in[12];
  const float* head_W1    = (const float*)d_in[13];
  const float* head_b1    = (const float*)d_in[14];
  const float* head_W2    = (const float*)d_in[15];
  const float* head_b2    = (const float*)d_in[16];

  unsigned short* wp = (unsigned short*)d_ws;   // 9*SZ + 8192 + 2*16384 ushorts ~ 4.8 MB

  dim3 blk(256);
  auto P = [&](const float* src, unsigned short* dst) {
    hipLaunchKernelGGL(pack_w, dim3(1024), blk, 0, stream, src, dst, 512, 512, 512);
  };
  P(enc_Wih + 0 * SZ, wp + 0 * SZ);
  P(enc_Wih + 1 * SZ, wp + 1 * SZ);
  P(enc_Whh + 0 * SZ, wp + 2 * SZ);
  P(enc_Whh + 1 * SZ, wp + 3 * SZ);
  P(dec_Wih + 0 * SZ, wp + 4 * SZ);
  P(dec_Wih + 1 * SZ, wp + 5 * SZ);
  P(dec_Whh + 0 * SZ, wp + 6 * SZ);
  P(dec_Whh + 1 * SZ, wp + 7 * SZ);
  P(head_W1, wp + 8 * SZ);
  hipLaunchKernelGGL(pack_w, dim3(32), blk, 0, stream, head_W2, wp + 9 * SZ, 2, 512, 512);
  hipLaunchKernelGGL(pack_w, dim3(64), blk, 0, stream, emb_veh_W, wp + 9 * SZ + 8192, 512, 6, 32);
  hipLaunchKernelGGL(pack_w, dim3(64), blk, 0, stream, emb_main_W, wp + 9 * SZ + 8192 + 16384, 512, 6, 32);

  hipLaunchKernelGGL(rnn_main, dim3(NBLK), dim3(1024), 0, stream,
                     x, (const unsigned short*)wp, enc_bih, enc_bhh, dec_bih, dec_bhh,
                     head_b1, head_b2, emb_main_b, emb_veh_b, (float*)d_out);
}